// Round 3
// baseline (453.903 us; speedup 1.0000x reference)
//
#include <hip/hip_runtime.h>
#include <hip/hip_bf16.h>

typedef __attribute__((ext_vector_type(8))) short bf16x8;
typedef __attribute__((ext_vector_type(4))) float f32x4;
typedef unsigned short u16;
typedef unsigned int u32;

#define ATT_SCALE 0.125f

__device__ __forceinline__ u16 f2bf(float f){
  __hip_bfloat16 h = __float2bfloat16(f);
  return *reinterpret_cast<u16*>(&h);
}
__device__ __forceinline__ float bf2f(u16 u){
  __hip_bfloat16 h;
  *reinterpret_cast<u16*>(&h) = u;
  return __bfloat162float(h);
}

__global__ __launch_bounds__(256) void cvt_kernel(const float* __restrict__ src,
                                                  u16* __restrict__ dst, int n4){
  int i = blockIdx.x*256 + threadIdx.x;
  if (i < n4){
    float4 v = reinterpret_cast<const float4*>(src)[i];
    ushort4 o;
    o.x = f2bf(v.x); o.y = f2bf(v.y); o.z = f2bf(v.z); o.w = f2bf(v.w);
    reinterpret_cast<ushort4*>(dst)[i] = o;
  }
}

// C = A(MxK) * B(NxK)^T, A/B bf16 row-major.
// MODE 0: QKV scatter -> Q[B,H,N,D](C0), K[B,H,N,D](C1), Vt[B,H,D,N](C2)
// MODE 3: fp32 store + bias (projection)
template<int BM, int BN, int MODE>
__global__ __launch_bounds__(256) void gemm_bt(
    const u16* __restrict__ A, const u16* __restrict__ B,
    void* __restrict__ C0, void* __restrict__ C1, void* __restrict__ C2,
    const float* __restrict__ bias,
    int M, int N, int K, int lda, int ldb)
{
  constexpr int BK = 32, LDT = 40;
  __shared__ u16 As[BM*LDT];
  __shared__ u16 Bs[BN*LDT];
  const int bm = blockIdx.x * BM, bn = blockIdx.y * BN;
  const int tid = threadIdx.x, lane = tid & 63, wv = tid >> 6;
  constexpr int WM = BM/2, WN = BN/2, FM = WM/16, FN = WN/16;
  const int wm = (wv >> 1) * WM, wn = (wv & 1) * WN;
  const int quad = lane >> 4, cl = lane & 15;
  f32x4 acc[FM][FN];
  #pragma unroll
  for (int i=0;i<FM;i++)
    #pragma unroll
    for (int j=0;j<FN;j++){ f32x4 zr = {0.f,0.f,0.f,0.f}; acc[i][j] = zr; }
  constexpr int AIT = (BM*BK)/(8*256);
  constexpr int BIT = (BN*BK)/(8*256);

  for (int kb = 0; kb < K; kb += BK){
    __syncthreads();
    #pragma unroll
    for (int sL=0; sL<AIT; sL++){
      int e = tid + sL*256, r = e >> 2, c8 = (e & 3) * 8;
      *reinterpret_cast<float4*>(&As[r*LDT + c8]) =
        *reinterpret_cast<const float4*>(A + (long)(bm + r)*lda + kb + c8);
    }
    #pragma unroll
    for (int sL=0; sL<BIT; sL++){
      int e = tid + sL*256, r = e >> 2, c8 = (e & 3) * 8;
      *reinterpret_cast<float4*>(&Bs[r*LDT + c8]) =
        *reinterpret_cast<const float4*>(B + (long)(bn + r)*ldb + kb + c8);
    }
    __syncthreads();
    bf16x8 af[FM], bfr[FN];
    #pragma unroll
    for (int i=0;i<FM;i++)
      af[i] = *reinterpret_cast<const bf16x8*>(&As[(wm + i*16 + cl)*LDT + quad*8]);
    #pragma unroll
    for (int j=0;j<FN;j++)
      bfr[j] = *reinterpret_cast<const bf16x8*>(&Bs[(wn + j*16 + cl)*LDT + quad*8]);
    #pragma unroll
    for (int i=0;i<FM;i++)
      #pragma unroll
      for (int j=0;j<FN;j++)
        acc[i][j] = __builtin_amdgcn_mfma_f32_16x16x32_bf16(af[i], bfr[j], acc[i][j], 0, 0, 0);
  }

  #pragma unroll
  for (int i=0;i<FM;i++)
  #pragma unroll
  for (int j=0;j<FN;j++)
  #pragma unroll
  for (int r=0;r<4;r++){
    int gm = bm + wm + i*16 + quad*4 + r;
    int gn = bn + wn + j*16 + cl;
    float v = acc[i][j][r];
    if (MODE == 0){
      int b_ = gm >> 10, n_ = gm & 1023;
      int t3 = (gn >= 1536) ? 2 : ((gn >= 768) ? 1 : 0);
      int rem = gn - t3*768;
      int h = rem >> 6, d = rem & 63;
      u16 hv = f2bf(v);
      if (t3 == 0)      ((u16*)C0)[((long)((b_*12 + h)*1024 + n_))*64 + d] = hv;
      else if (t3 == 1) ((u16*)C1)[((long)((b_*12 + h)*1024 + n_))*64 + d] = hv;
      else              ((u16*)C2)[((long)((b_*12 + h)*64 + d))*1024 + n_] = hv;
    } else {
      ((float*)C0)[(long)gm*N + gn] = v + bias[gn];
    }
  }
}

// Fused QK^T + talking-heads premix + exp. Grid (mt=32, nt=16, b=4), 256 thr.
// Wave patch: 32n x 16m (2 n-frags). All 12 heads' premixed logits kept in
// C-layout regs (Dg, 96 VGPR), heads streamed through 2x2 MFMAs with Q/K
// fragments loaded DIRECTLY from global (no LDS, no barriers).
// Epilogue: += rowsum(w_pre)[g]*mask, exp, store unnormalized E (bf16),
// atomicAdd partial L_g[n] (fp32) after intra-quad shfl reduction over m.
__global__ __launch_bounds__(256) void se_kernel(
    const u16* __restrict__ Q, const u16* __restrict__ K,
    u16* __restrict__ E, float* __restrict__ L,
    const float* __restrict__ mask, const float* __restrict__ w_pre)
{
  const int mt = blockIdx.x, nt = blockIdx.y, b = blockIdx.z;
  const int t = threadIdx.x, wv = t >> 6, lane = t & 63;
  const int quad = lane >> 4, cl = lane & 15;
  const int n0 = nt*64 + (wv >> 1)*32;
  const int m0 = mt*32 + (wv & 1)*16;
  const int m0c = m0 + cl;

  f32x4 Dg[12][2];
  #pragma unroll
  for (int g=0; g<12; g++){
    f32x4 zr = {0.f,0.f,0.f,0.f};
    Dg[g][0] = zr; Dg[g][1] = zr;
  }
  const f32x4 z4 = {0.f,0.f,0.f,0.f};

  #pragma unroll 2
  for (int h=0; h<12; h++){
    const u16* Qh = Q + ((long)(b*12 + h))*1024*64;
    const u16* Kh = K + ((long)(b*12 + h))*1024*64;
    bf16x8 a0  = *reinterpret_cast<const bf16x8*>(Qh + (n0      + cl)*64 + quad*8);
    bf16x8 a0b = *reinterpret_cast<const bf16x8*>(Qh + (n0      + cl)*64 + 32 + quad*8);
    bf16x8 a1  = *reinterpret_cast<const bf16x8*>(Qh + (n0 + 16 + cl)*64 + quad*8);
    bf16x8 a1b = *reinterpret_cast<const bf16x8*>(Qh + (n0 + 16 + cl)*64 + 32 + quad*8);
    bf16x8 b0  = *reinterpret_cast<const bf16x8*>(Kh + (m0      + cl)*64 + quad*8);
    bf16x8 b0b = *reinterpret_cast<const bf16x8*>(Kh + (m0      + cl)*64 + 32 + quad*8);
    f32x4 s0 = __builtin_amdgcn_mfma_f32_16x16x32_bf16(a0,  b0,  z4, 0, 0, 0);
    s0       = __builtin_amdgcn_mfma_f32_16x16x32_bf16(a0b, b0b, s0, 0, 0, 0);
    f32x4 s1 = __builtin_amdgcn_mfma_f32_16x16x32_bf16(a1,  b0,  z4, 0, 0, 0);
    s1       = __builtin_amdgcn_mfma_f32_16x16x32_bf16(a1b, b0b, s1, 0, 0, 0);
    #pragma unroll
    for (int g=0; g<12; g++){
      float w = w_pre[g*12 + h] * ATT_SCALE;   // uniform -> s_load
      Dg[g][0] += s0 * w;
      Dg[g][1] += s1 * w;
    }
  }

  float rs[12];
  #pragma unroll
  for (int g=0; g<12; g++){
    float v = 0.f;
    #pragma unroll
    for (int h=0; h<12; h++) v += w_pre[g*12 + h];
    rs[g] = v;
  }

  #pragma unroll
  for (int f=0; f<2; f++)
  #pragma unroll
  for (int r=0; r<4; r++){
    int n = n0 + f*16 + quad*4 + r;
    float mv = mask[((long)(b*1024 + n))*1024 + m0c];
    #pragma unroll
    for (int g=0; g<12; g++){
      float e = __expf(Dg[g][f][r] + rs[g]*mv);
      E[((long)((b*12 + g)*1024 + n))*1024 + m0c] = f2bf(e);
      float v = e;
      v += __shfl_xor(v, 1); v += __shfl_xor(v, 2);
      v += __shfl_xor(v, 4); v += __shfl_xor(v, 8);
      if (cl == 0) atomicAdd(&L[(b*12 + g)*1024 + n], v);
    }
  }
}

// Fused postmix + PV. Grid (nt=64, b=4), 512 thr = 8 waves.
// Wave (hset = wv>>1 owns 3 heads, mp = wv&1 owns half the m range).
// Per 32-m chunk: E_g A-fragments loaded b128 from global (layout matches
// MFMA A-layout: row=cl, k=quad*8+j), normalized by 1/L_g[n] and postmixed
// into P_h in-register, then MFMA against Vt B-fragments (b128 from global).
// mp pairs reduced via LDS; store tmp[b][n][h*64+d] bf16.
__global__ __launch_bounds__(512) void pv_kernel(
    const u16* __restrict__ E, const u16* __restrict__ Vt,
    const float* __restrict__ L, u16* __restrict__ tmp,
    const float* __restrict__ w_post)
{
  __shared__ float red[4*64*52];
  const int nt = blockIdx.x, b = blockIdx.y;
  const int t = threadIdx.x, wv = t >> 6, lane = t & 63;
  const int quad = lane >> 4, cl = lane & 15;
  const int hset = wv >> 1, mp = wv & 1;
  const int n0 = nt*16;

  float invL[12];
  #pragma unroll
  for (int g=0; g<12; g++)
    invL[g] = 1.0f / L[(b*12 + g)*1024 + n0 + cl];

  f32x4 O[3][4];
  #pragma unroll
  for (int hh=0; hh<3; hh++)
    #pragma unroll
    for (int df=0; df<4; df++){ f32x4 zr = {0.f,0.f,0.f,0.f}; O[hh][df] = zr; }

  for (int c = mp*16; c < mp*16 + 16; c++){
    const long m0 = (long)c*32 + quad*8;
    float P[3][8];
    #pragma unroll
    for (int hh=0; hh<3; hh++)
      #pragma unroll
      for (int j=0; j<8; j++) P[hh][j] = 0.f;

    #pragma unroll
    for (int g=0; g<12; g++){
      union { bf16x8 v; u16 s[8]; } ef;
      ef.v = *reinterpret_cast<const bf16x8*>(
          E + ((long)((b*12 + g)*1024 + n0 + cl))*1024 + m0);
      #pragma unroll
      for (int j=0; j<8; j++){
        float en = bf2f(ef.s[j]) * invL[g];
        #pragma unroll
        for (int hh=0; hh<3; hh++)
          P[hh][j] += w_post[(hset*3 + hh)*12 + g] * en;   // uniform -> s_load
      }
    }
    #pragma unroll
    for (int hh=0; hh<3; hh++){
      int h = hset*3 + hh;
      union { bf16x8 v; u16 s[8]; } pa;
      #pragma unroll
      for (int j=0; j<8; j++) pa.s[j] = f2bf(P[hh][j]);
      #pragma unroll
      for (int df=0; df<4; df++){
        bf16x8 vb = *reinterpret_cast<const bf16x8*>(
            Vt + ((long)((b*12 + h)*64 + df*16 + cl))*1024 + m0);
        O[hh][df] = __builtin_amdgcn_mfma_f32_16x16x32_bf16(pa.v, vb, O[hh][df], 0, 0, 0);
      }
    }
  }

  if (mp == 1){
    float* base = red + (hset*64 + lane)*52;
    #pragma unroll
    for (int hh=0; hh<3; hh++)
      #pragma unroll
      for (int df=0; df<4; df++)
        *reinterpret_cast<f32x4*>(base + (hh*4 + df)*4) = O[hh][df];
  }
  __syncthreads();
  if (mp == 0){
    const float* base = red + (hset*64 + lane)*52;
    #pragma unroll
    for (int hh=0; hh<3; hh++){
      int h = hset*3 + hh;
      #pragma unroll
      for (int df=0; df<4; df++){
        f32x4 o = O[hh][df] + *reinterpret_cast<const f32x4*>(base + (hh*4 + df)*4);
        #pragma unroll
        for (int r=0; r<4; r++){
          int n = n0 + quad*4 + r;
          tmp[((long)(b*1024 + n))*768 + h*64 + df*16 + cl] = f2bf(o[r]);
        }
      }
    }
  }
}

extern "C" void kernel_launch(void* const* d_in, const int* in_sizes, int n_in,
                              void* d_out, int out_size, void* d_ws, size_t ws_size,
                              hipStream_t stream)
{
  const float* x      = (const float*)d_in[0];
  const float* mask   = (const float*)d_in[1];
  const float* w_qkv  = (const float*)d_in[2];
  const float* w_proj = (const float*)d_in[3];
  const float* b_proj = (const float*)d_in[4];
  const float* w_pre  = (const float*)d_in[5];
  const float* w_post = (const float*)d_in[6];
  float* out = (float*)d_out;

  u16* xb     = (u16*)d_ws;            // 4096x768   (reused as tmp after QKV gemm)
  u16* wqkvb  = xb     + 4096l*768;
  u16* wprojb = wqkvb  + 2304l*768;
  u16* Qb     = wprojb + 768l*768;
  u16* Kb     = Qb     + 48l*1024*64;
  u16* Vtb    = Kb     + 48l*1024*64;
  u16* Eb     = Vtb    + 48l*1024*64;
  float* Lf   = (float*)(Eb + 48l*1024*1024);
  u16* tmpb   = xb;                    // overlay: xb dead after QKV gemm
  size_t need = ((size_t)((u16*)Lf - xb) + 2ul*48*1024) * sizeof(u16);
  if (ws_size < need) return;

  hipMemsetAsync(Lf, 0, 48l*1024*sizeof(float), stream);

  cvt_kernel<<<(4096*768/4 + 255)/256, 256, 0, stream>>>(x,      xb,     4096*768/4);
  cvt_kernel<<<(2304*768/4 + 255)/256, 256, 0, stream>>>(w_qkv,  wqkvb,  2304*768/4);
  cvt_kernel<<<(768*768/4  + 255)/256, 256, 0, stream>>>(w_proj, wprojb, 768*768/4);

  dim3 gq(4096/128, 2304/128, 1);
  gemm_bt<128,128,0><<<gq, 256, 0, stream>>>(xb, wqkvb, Qb, Kb, Vtb, nullptr,
      4096, 2304, 768, 768, 768);

  dim3 gse(32, 16, 4);
  se_kernel<<<gse, 256, 0, stream>>>(Qb, Kb, Eb, Lf, mask, w_pre);

  dim3 gpv(64, 4);
  pv_kernel<<<gpv, 512, 0, stream>>>(Eb, Vtb, Lf, tmpb, w_post);

  dim3 go(4096/128, 768/128, 1);
  gemm_bt<128,128,3><<<go, 256, 0, stream>>>(tmpb, wprojb, out, nullptr, nullptr, b_proj,
      4096, 768, 768, 768, 768);
}

// Round 4
// 430.661 us; speedup vs baseline: 1.0540x; 1.0540x over previous
//
#include <hip/hip_runtime.h>
#include <hip/hip_bf16.h>

typedef __attribute__((ext_vector_type(8))) short bf16x8;
typedef __attribute__((ext_vector_type(4))) float f32x4;
typedef unsigned short u16;
typedef unsigned int u32;

#define ATT_SCALE 0.125f

__device__ __forceinline__ u16 f2bf(float f){
  __hip_bfloat16 h = __float2bfloat16(f);
  return *reinterpret_cast<u16*>(&h);
}

__global__ __launch_bounds__(256) void cvt_kernel(const float* __restrict__ src,
                                                  u16* __restrict__ dst, int n4){
  int i = blockIdx.x*256 + threadIdx.x;
  if (i < n4){
    float4 v = reinterpret_cast<const float4*>(src)[i];
    ushort4 o;
    o.x = f2bf(v.x); o.y = f2bf(v.y); o.z = f2bf(v.z); o.w = f2bf(v.w);
    reinterpret_cast<ushort4*>(dst)[i] = o;
  }
}

// C = A(MxK) * B(NxK)^T, B bf16 row-major; A bf16 (CA=false) or fp32 (CA=true,
// converted during LDS staging).
// MODE 0: QKV scatter -> Q[B,H,N,D](C0), K[B,H,N,D](C1), Vt[B,H,D,N](C2)
// MODE 3: fp32 store + bias (projection)
template<int BM, int BN, int MODE, bool CA>
__global__ __launch_bounds__(256) void gemm_bt(
    const void* __restrict__ A, const u16* __restrict__ B,
    void* __restrict__ C0, void* __restrict__ C1, void* __restrict__ C2,
    const float* __restrict__ bias,
    int M, int N, int K, int lda, int ldb)
{
  constexpr int BK = 32, LDT = 40;
  __shared__ u16 As[BM*LDT];
  __shared__ u16 Bs[BN*LDT];
  const int bm = blockIdx.x * BM, bn = blockIdx.y * BN;
  const int tid = threadIdx.x, lane = tid & 63, wv = tid >> 6;
  constexpr int WM = BM/2, WN = BN/2, FM = WM/16, FN = WN/16;
  const int wm = (wv >> 1) * WM, wn = (wv & 1) * WN;
  const int quad = lane >> 4, cl = lane & 15;
  f32x4 acc[FM][FN];
  #pragma unroll
  for (int i=0;i<FM;i++)
    #pragma unroll
    for (int j=0;j<FN;j++){ f32x4 zr = {0.f,0.f,0.f,0.f}; acc[i][j] = zr; }
  constexpr int AIT = (BM*BK)/(8*256);
  constexpr int BIT = (BN*BK)/(8*256);

  for (int kb = 0; kb < K; kb += BK){
    __syncthreads();
    #pragma unroll
    for (int sL=0; sL<AIT; sL++){
      int e = tid + sL*256, r = e >> 2, c8 = (e & 3) * 8;
      if (CA){
        const float* Af = (const float*)A;
        float4 lo = *reinterpret_cast<const float4*>(Af + (long)(bm + r)*lda + kb + c8);
        float4 hi = *reinterpret_cast<const float4*>(Af + (long)(bm + r)*lda + kb + c8 + 4);
        ushort4 plo, phi;
        plo.x=f2bf(lo.x); plo.y=f2bf(lo.y); plo.z=f2bf(lo.z); plo.w=f2bf(lo.w);
        phi.x=f2bf(hi.x); phi.y=f2bf(hi.y); phi.z=f2bf(hi.z); phi.w=f2bf(hi.w);
        *reinterpret_cast<ushort4*>(&As[r*LDT + c8]) = plo;
        *reinterpret_cast<ushort4*>(&As[r*LDT + c8 + 4]) = phi;
      } else {
        *reinterpret_cast<float4*>(&As[r*LDT + c8]) =
          *reinterpret_cast<const float4*>((const u16*)A + (long)(bm + r)*lda + kb + c8);
      }
    }
    #pragma unroll
    for (int sL=0; sL<BIT; sL++){
      int e = tid + sL*256, r = e >> 2, c8 = (e & 3) * 8;
      *reinterpret_cast<float4*>(&Bs[r*LDT + c8]) =
        *reinterpret_cast<const float4*>(B + (long)(bn + r)*ldb + kb + c8);
    }
    __syncthreads();
    bf16x8 af[FM], bfr[FN];
    #pragma unroll
    for (int i=0;i<FM;i++)
      af[i] = *reinterpret_cast<const bf16x8*>(&As[(wm + i*16 + cl)*LDT + quad*8]);
    #pragma unroll
    for (int j=0;j<FN;j++)
      bfr[j] = *reinterpret_cast<const bf16x8*>(&Bs[(wn + j*16 + cl)*LDT + quad*8]);
    #pragma unroll
    for (int i=0;i<FM;i++)
      #pragma unroll
      for (int j=0;j<FN;j++)
        acc[i][j] = __builtin_amdgcn_mfma_f32_16x16x32_bf16(af[i], bfr[j], acc[i][j], 0, 0, 0);
  }

  #pragma unroll
  for (int i=0;i<FM;i++)
  #pragma unroll
  for (int j=0;j<FN;j++)
  #pragma unroll
  for (int r=0;r<4;r++){
    int gm = bm + wm + i*16 + quad*4 + r;
    int gn = bn + wn + j*16 + cl;
    float v = acc[i][j][r];
    if (MODE == 0){
      int b_ = gm >> 10, n_ = gm & 1023;
      int t3 = (gn >= 1536) ? 2 : ((gn >= 768) ? 1 : 0);
      int rem = gn - t3*768;
      int h = rem >> 6, d = rem & 63;
      u16 hv = f2bf(v);
      if (t3 == 0)      ((u16*)C0)[((long)((b_*12 + h)*1024 + n_))*64 + d] = hv;
      else if (t3 == 1) ((u16*)C1)[((long)((b_*12 + h)*1024 + n_))*64 + d] = hv;
      else              ((u16*)C2)[((long)((b_*12 + h)*64 + d))*1024 + n_] = hv;
    } else {
      ((float*)C0)[(long)gm*N + gn] = v + bias[gn];
    }
  }
}

// Pass 1: QK^T + premix + exp -> L_g[n] partial sums via atomics. No score
// materialization. Grid (nt=64, mq=4, b=4), 256 thr = 4 waves.
// Wave: n-tile 16 (block-shared), m-range = mq*256 + wv*64, 4 chunks of 16 m.
__global__ __launch_bounds__(256) void p1_kernel(
    const u16* __restrict__ Q, const u16* __restrict__ K,
    float* __restrict__ L, const float* __restrict__ mask,
    const float* __restrict__ w_pre)
{
  const int nt = blockIdx.x, mq = blockIdx.y, b = blockIdx.z;
  const int t = threadIdx.x, wv = t >> 6, lane = t & 63;
  const int quad = lane >> 4, cl = lane & 15;
  const int n0 = nt*16;
  const f32x4 z4 = {0.f,0.f,0.f,0.f};

  float rs[12];
  #pragma unroll
  for (int g=0; g<12; g++){
    float v = 0.f;
    #pragma unroll
    for (int h=0; h<12; h++) v += w_pre[g*12 + h];
    rs[g] = v;
  }

  float Lacc[12][4];
  #pragma unroll
  for (int g=0; g<12; g++)
    #pragma unroll
    for (int r=0; r<4; r++) Lacc[g][r] = 0.f;

  for (int c=0; c<4; c++){
    const int ms = mq*256 + wv*64 + c*16;
    f32x4 Dg[12];
    #pragma unroll
    for (int g=0; g<12; g++) Dg[g] = z4;
    #pragma unroll 2
    for (int h=0; h<12; h++){
      const u16* Qh = Q + ((long)(b*12 + h))*65536;
      const u16* Kh = K + ((long)(b*12 + h))*65536;
      bf16x8 a0  = *reinterpret_cast<const bf16x8*>(Qh + (n0 + cl)*64 + quad*8);
      bf16x8 a0b = *reinterpret_cast<const bf16x8*>(Qh + (n0 + cl)*64 + 32 + quad*8);
      bf16x8 b0  = *reinterpret_cast<const bf16x8*>(Kh + (ms + cl)*64 + quad*8);
      bf16x8 b0b = *reinterpret_cast<const bf16x8*>(Kh + (ms + cl)*64 + 32 + quad*8);
      f32x4 s = __builtin_amdgcn_mfma_f32_16x16x32_bf16(a0,  b0,  z4, 0, 0, 0);
      s       = __builtin_amdgcn_mfma_f32_16x16x32_bf16(a0b, b0b, s,  0, 0, 0);
      #pragma unroll
      for (int g=0; g<12; g++){
        float w = w_pre[g*12 + h] * ATT_SCALE;
        Dg[g] += s * w;
      }
    }
    #pragma unroll
    for (int r=0; r<4; r++){
      float mv = mask[((long)(b*1024 + n0 + quad*4 + r))*1024 + ms + cl];
      #pragma unroll
      for (int g=0; g<12; g++)
        Lacc[g][r] += __expf(Dg[g][r] + rs[g]*mv);
    }
  }

  #pragma unroll
  for (int g=0; g<12; g++)
    #pragma unroll
    for (int r=0; r<4; r++){
      float v = Lacc[g][r];
      v += __shfl_xor(v, 1); v += __shfl_xor(v, 2);
      v += __shfl_xor(v, 4); v += __shfl_xor(v, 8);
      if (cl == 0) atomicAdd(&L[(b*12 + g)*1024 + n0 + quad*4 + r], v);
    }
}

// Pass 2: recompute QK^T + premix + exp, x invL, postmix in-register, P~ via
// LDS transpose (C-layout -> A-layout), MFMA vs Vt, fp32 atomicAdd into tmp32.
// Grid (nt=64, mq=4, b=4), 256 thr. LDS tile: 12 h x [16 n][72-padded m64].
#define LDM 72
#define HOFF (16*LDM)

__global__ __launch_bounds__(256) void p2_kernel(
    const u16* __restrict__ Q, const u16* __restrict__ K,
    const u16* __restrict__ Vt, const float* __restrict__ L,
    float* __restrict__ tmp32, const float* __restrict__ mask,
    const float* __restrict__ w_pre, const float* __restrict__ w_post)
{
  __shared__ u16 Pt[12*HOFF];
  __shared__ float invLs[192];
  const int nt = blockIdx.x, mq = blockIdx.y, b = blockIdx.z;
  const int t = threadIdx.x, wv = t >> 6, lane = t & 63;
  const int quad = lane >> 4, cl = lane & 15;
  const int n0 = nt*16;
  const f32x4 z4 = {0.f,0.f,0.f,0.f};

  if (t < 192){
    int g = t >> 4, n = t & 15;
    invLs[t] = 1.0f / L[(b*12 + g)*1024 + n0 + n];
  }

  float rs[12];
  #pragma unroll
  for (int g=0; g<12; g++){
    float v = 0.f;
    #pragma unroll
    for (int h=0; h<12; h++) v += w_pre[g*12 + h];
    rs[g] = v;
  }

  f32x4 O[3][4];
  #pragma unroll
  for (int hh=0; hh<3; hh++)
    #pragma unroll
    for (int df=0; df<4; df++) O[hh][df] = z4;

  __syncthreads();

  for (int c=0; c<4; c++){
    const int ms = mq*256 + c*64 + wv*16;
    f32x4 Dg[12];
    #pragma unroll
    for (int g=0; g<12; g++) Dg[g] = z4;
    #pragma unroll 2
    for (int h=0; h<12; h++){
      const u16* Qh = Q + ((long)(b*12 + h))*65536;
      const u16* Kh = K + ((long)(b*12 + h))*65536;
      bf16x8 a0  = *reinterpret_cast<const bf16x8*>(Qh + (n0 + cl)*64 + quad*8);
      bf16x8 a0b = *reinterpret_cast<const bf16x8*>(Qh + (n0 + cl)*64 + 32 + quad*8);
      bf16x8 b0  = *reinterpret_cast<const bf16x8*>(Kh + (ms + cl)*64 + quad*8);
      bf16x8 b0b = *reinterpret_cast<const bf16x8*>(Kh + (ms + cl)*64 + 32 + quad*8);
      f32x4 s = __builtin_amdgcn_mfma_f32_16x16x32_bf16(a0,  b0,  z4, 0, 0, 0);
      s       = __builtin_amdgcn_mfma_f32_16x16x32_bf16(a0b, b0b, s,  0, 0, 0);
      #pragma unroll
      for (int g=0; g<12; g++){
        float w = w_pre[g*12 + h] * ATT_SCALE;
        Dg[g] += s * w;
      }
    }
    // exp + normalize (invL folded here)
    float mv[4];
    #pragma unroll
    for (int r=0; r<4; r++)
      mv[r] = mask[((long)(b*1024 + n0 + quad*4 + r))*1024 + ms + cl];
    #pragma unroll
    for (int g=0; g<12; g++){
      f32x4 il = *reinterpret_cast<const f32x4*>(&invLs[g*16 + quad*4]);
      #pragma unroll
      for (int r=0; r<4; r++)
        Dg[g][r] = __expf(Dg[g][r] + rs[g]*mv[r]) * il[r];
    }
    // postmix all 12 h, write C-layout into LDS tile (transpose medium)
    #pragma unroll
    for (int h=0; h<12; h++){
      f32x4 p = z4;
      #pragma unroll
      for (int g=0; g<12; g++)
        p += Dg[g] * w_post[h*12 + g];
      int base = h*HOFF + quad*4*LDM + wv*16 + cl;
      #pragma unroll
      for (int r=0; r<4; r++)
        Pt[base + r*LDM] = f2bf(p[r]);
    }
    __syncthreads();
    // PV: wave owns 3 heads; A-frags b128 from LDS, B-frags b128 from Vt
    #pragma unroll
    for (int hh=0; hh<3; hh++){
      int h = wv*3 + hh;
      #pragma unroll
      for (int kk=0; kk<2; kk++){
        bf16x8 af = *reinterpret_cast<const bf16x8*>(
            &Pt[h*HOFF + cl*LDM + kk*32 + quad*8]);
        #pragma unroll
        for (int df=0; df<4; df++){
          bf16x8 vb = *reinterpret_cast<const bf16x8*>(
              Vt + ((long)((b*12 + h)*64 + df*16 + cl))*1024 + mq*256 + c*64 + kk*32 + quad*8);
          O[hh][df] = __builtin_amdgcn_mfma_f32_16x16x32_bf16(af, vb, O[hh][df], 0, 0, 0);
        }
      }
    }
    __syncthreads();
  }

  #pragma unroll
  for (int hh=0; hh<3; hh++)
    #pragma unroll
    for (int df=0; df<4; df++)
      #pragma unroll
      for (int r=0; r<4; r++)
        atomicAdd(&tmp32[((long)(b*1024 + n0 + quad*4 + r))*768
                         + (wv*3 + hh)*64 + df*16 + cl], O[hh][df][r]);
}

extern "C" void kernel_launch(void* const* d_in, const int* in_sizes, int n_in,
                              void* d_out, int out_size, void* d_ws, size_t ws_size,
                              hipStream_t stream)
{
  const float* x      = (const float*)d_in[0];
  const float* mask   = (const float*)d_in[1];
  const float* w_qkv  = (const float*)d_in[2];
  const float* w_proj = (const float*)d_in[3];
  const float* b_proj = (const float*)d_in[4];
  const float* w_pre  = (const float*)d_in[5];
  const float* w_post = (const float*)d_in[6];
  float* out = (float*)d_out;

  u16* xb     = (u16*)d_ws;
  u16* wqkvb  = xb     + 4096l*768;
  u16* wprojb = wqkvb  + 2304l*768;
  u16* Qb     = wprojb + 768l*768;
  u16* Kb     = Qb     + 48l*1024*64;
  u16* Vtb    = Kb     + 48l*1024*64;
  float* Lf   = (float*)(Vtb + 48l*1024*64);
  float* tmp32 = Lf + 48l*1024;
  size_t need = (size_t)((char*)(tmp32 + 4096l*768) - (char*)d_ws);
  if (ws_size < need) return;

  hipMemsetAsync(Lf, 0, 48l*1024*sizeof(float), stream);
  hipMemsetAsync(tmp32, 0, 4096l*768*sizeof(float), stream);

  cvt_kernel<<<(4096*768/4 + 255)/256, 256, 0, stream>>>(x,      xb,     4096*768/4);
  cvt_kernel<<<(2304*768/4 + 255)/256, 256, 0, stream>>>(w_qkv,  wqkvb,  2304*768/4);
  cvt_kernel<<<(768*768/4  + 255)/256, 256, 0, stream>>>(w_proj, wprojb, 768*768/4);

  dim3 gq(4096/128, 2304/128, 1);
  gemm_bt<128,128,0,false><<<gq, 256, 0, stream>>>(xb, wqkvb, Qb, Kb, Vtb, nullptr,
      4096, 2304, 768, 768, 768);

  dim3 gp(64, 4, 4);
  p1_kernel<<<gp, 256, 0, stream>>>(Qb, Kb, Lf, mask, w_pre);
  p2_kernel<<<gp, 256, 0, stream>>>(Qb, Kb, Vtb, Lf, tmp32, mask, w_pre, w_post);

  dim3 go(4096/128, 768/128, 1);
  gemm_bt<128,128,3,true><<<go, 256, 0, stream>>>(tmp32, wprojb, out, nullptr, nullptr, b_proj,
      4096, 768, 768, 768, 768);
}

// Round 6
// 280.511 us; speedup vs baseline: 1.6181x; 1.5353x over previous
//
#include <hip/hip_runtime.h>
#include <hip/hip_bf16.h>

typedef __attribute__((ext_vector_type(8))) short bf16x8;
typedef __attribute__((ext_vector_type(4))) float f32x4;
typedef unsigned short u16;
typedef unsigned int u32;
typedef unsigned long long u64;

#define ATT_SCALE 0.125f

__device__ __forceinline__ u16 f2bf(float f){
  __hip_bfloat16 h = __float2bfloat16(f);
  return *reinterpret_cast<u16*>(&h);
}

__global__ __launch_bounds__(256) void cvt_kernel(const float* __restrict__ src,
                                                  u16* __restrict__ dst, int n4){
  int i = blockIdx.x*256 + threadIdx.x;
  if (i < n4){
    float4 v = reinterpret_cast<const float4*>(src)[i];
    ushort4 o;
    o.x = f2bf(v.x); o.y = f2bf(v.y); o.z = f2bf(v.z); o.w = f2bf(v.w);
    reinterpret_cast<ushort4*>(dst)[i] = o;
  }
}

// C = A(MxK) * B(NxK)^T, A/B bf16 row-major, batched over blockIdx.z.
// MODE 0: QKV scatter -> Q[B,H,N,D](C0), K[B,H,N,D](C1), Vt[B,H,D,N](C2)
// MODE 1: bf16 store, batch stride sC (scores)
// MODE 2: PV -> tmp[B,N,H,D] bf16 (z = b*12+h)
// MODE 3: fp32 store + bias (projection)
template<int BM, int BN, int BK, int MODE>
__global__ __launch_bounds__(256) void gemm_bt(
    const u16* __restrict__ A, const u16* __restrict__ B,
    void* __restrict__ C0, void* __restrict__ C1, void* __restrict__ C2,
    const float* __restrict__ bias,
    int M, int N, int K, int lda, int ldb, long sA, long sB, long sC)
{
  constexpr int LDT = BK + 8;
  __shared__ u16 As[BM*LDT];
  __shared__ u16 Bs[BN*LDT];
  const int z = blockIdx.z;
  const u16* Ab = A + (long)z * sA;
  const u16* Bb = B + (long)z * sB;
  const int bm = blockIdx.x * BM, bn = blockIdx.y * BN;
  const int tid = threadIdx.x, lane = tid & 63, wv = tid >> 6;
  constexpr int WM = BM/2, WN = BN/2, FM = WM/16, FN = WN/16;
  const int wm = (wv >> 1) * WM, wn = (wv & 1) * WN;
  const int quad = lane >> 4, cl = lane & 15;
  f32x4 acc[FM][FN];
  #pragma unroll
  for (int i=0;i<FM;i++)
    #pragma unroll
    for (int j=0;j<FN;j++){ f32x4 zr = {0.f,0.f,0.f,0.f}; acc[i][j] = zr; }
  constexpr int KV = BK/8;
  constexpr int AIT = (BM*BK)/(8*256);
  constexpr int BIT = (BN*BK)/(8*256);

  for (int kb = 0; kb < K; kb += BK){
    __syncthreads();
    #pragma unroll
    for (int sL=0; sL<AIT; sL++){
      int e = tid + sL*256, r = e / KV, c8 = (e % KV) * 8;
      *reinterpret_cast<float4*>(&As[r*LDT + c8]) =
        *reinterpret_cast<const float4*>(Ab + (long)(bm + r)*lda + kb + c8);
    }
    #pragma unroll
    for (int sL=0; sL<BIT; sL++){
      int e = tid + sL*256, r = e / KV, c8 = (e % KV) * 8;
      *reinterpret_cast<float4*>(&Bs[r*LDT + c8]) =
        *reinterpret_cast<const float4*>(Bb + (long)(bn + r)*ldb + kb + c8);
    }
    __syncthreads();
    #pragma unroll
    for (int kk=0; kk<BK; kk+=32){
      bf16x8 af[FM], bfr[FN];
      #pragma unroll
      for (int i=0;i<FM;i++)
        af[i] = *reinterpret_cast<const bf16x8*>(&As[(wm + i*16 + cl)*LDT + kk + quad*8]);
      #pragma unroll
      for (int j=0;j<FN;j++)
        bfr[j] = *reinterpret_cast<const bf16x8*>(&Bs[(wn + j*16 + cl)*LDT + kk + quad*8]);
      #pragma unroll
      for (int i=0;i<FM;i++)
        #pragma unroll
        for (int j=0;j<FN;j++)
          acc[i][j] = __builtin_amdgcn_mfma_f32_16x16x32_bf16(af[i], bfr[j], acc[i][j], 0, 0, 0);
    }
  }

  #pragma unroll
  for (int i=0;i<FM;i++)
  #pragma unroll
  for (int j=0;j<FN;j++)
  #pragma unroll
  for (int r=0;r<4;r++){
    int gm = bm + wm + i*16 + quad*4 + r;
    int gn = bn + wn + j*16 + cl;
    float v = acc[i][j][r];
    if (MODE == 0){
      int b_ = gm >> 10, n_ = gm & 1023;
      int t3 = (gn >= 1536) ? 2 : ((gn >= 768) ? 1 : 0);
      int rem = gn - t3*768;
      int h = rem >> 6, d = rem & 63;
      u16 hv = f2bf(v);
      if (t3 == 0)      ((u16*)C0)[((long)((b_*12 + h)*1024 + n_))*64 + d] = hv;
      else if (t3 == 1) ((u16*)C1)[((long)((b_*12 + h)*1024 + n_))*64 + d] = hv;
      else              ((u16*)C2)[((long)((b_*12 + h)*64 + d))*1024 + n_] = hv;
    } else if (MODE == 1){
      ((u16*)C0)[(long)z*sC + (long)gm*N + gn] = f2bf(v);
    } else if (MODE == 2){
      int b_ = z / 12, h = z - b_*12;
      ((u16*)C0)[((long)((b_*1024 + gm)*12 + h))*64 + gn] = f2bf(v);
    } else {
      ((float*)C0)[(long)gm*N + gn] = v + bias[gn];
    }
  }
}

// MFMA talking-heads mix v3 (NaN-fixed): one block per (b,n). S staged
// TRANSPOSED into LDS slab[m][28] (stride 14 words -> <=2-way banks):
// slots 0..11 = S[h], 12..15 zeroed. B-fragment k=16..31 NEVER read from LDS
// (quads 2,3 use register zeros) -- A is zero there, and 0*garbage-NaN = NaN
// was the round-5 failure. premix: D[g][m] = (w_pre*scale*log2e)[g][h] x slab
// (MFMA), exp2(D + rowsum(w_pre)*log2e*mask), E packed back IN PLACE (slot=g)
// via one ds_write_b64. L_g = block reduce. postmix:
// (w_post*diag(1/L))[h][g] x E (MFMA), store C-layout to S.
__global__ __launch_bounds__(256) void mix3_kernel(
    u16* __restrict__ S, const float* __restrict__ mask,
    const float* __restrict__ w_pre, const float* __restrict__ w_post)
{
  __shared__ u16 slab[1024*28];
  __shared__ float maskS[1024];
  __shared__ float Lred[4][16];
  __shared__ float invLs[16];

  const int bid = blockIdx.x;
  const int b = bid >> 10, n = bid & 1023;
  const int t = threadIdx.x, wv = t >> 6, lane = t & 63;
  const int quad = lane >> 4, cl = lane & 15;
  const float LOG2E = 1.4426950408889634f;

  // stage S[b][h][n][*] -> slab[m][h]; zero slots 12..15
  #pragma unroll
  for (int h = 0; h < 12; h++){
    const u16* Srow = S + ((long)((b*12 + h)*1024 + n))*1024;
    #pragma unroll
    for (int p = 0; p < 4; p++){
      int m = t + p*256;
      slab[m*28 + h] = Srow[m];
    }
  }
  #pragma unroll
  for (int p = 0; p < 4; p++){
    int m = t + p*256;
    *reinterpret_cast<u64*>(&slab[m*28 + 12]) = 0ull;
  }
  *reinterpret_cast<float4*>(&maskS[t*4]) =
      *reinterpret_cast<const float4*>(mask + ((long)(b*1024 + n))*1024 + t*4);

  union FragU { bf16x8 v; u64 d[2]; u16 s[8]; };
  FragU a_pre;
  #pragma unroll
  for (int j = 0; j < 8; j++){
    int k = quad*8 + j;   // k = h
    a_pre.s[j] = (cl < 12 && k < 12) ? f2bf(w_pre[cl*12 + k] * (ATT_SCALE*LOG2E)) : (u16)0;
  }
  float rs_[4];
  #pragma unroll
  for (int r = 0; r < 4; r++){
    int g = quad*4 + r;
    float v = 0.f;
    if (g < 12)
      for (int h = 0; h < 12; h++) v += w_pre[g*12 + h];
    rs_[r] = v * LOG2E;
  }
  __syncthreads();

  const f32x4 z4 = {0.f,0.f,0.f,0.f};
  float Lacc[4] = {0.f,0.f,0.f,0.f};
  const bool qlo = (quad < 2);
  // premix + exp sweep over wave's 256-m strip
  #pragma unroll
  for (int j = 0; j < 16; j++){
    int mcol = wv*256 + j*16 + cl;
    FragU bs;
    bs.d[0] = qlo ? *reinterpret_cast<const u64*>(&slab[mcol*28 + quad*8])     : 0ull;
    bs.d[1] = qlo ? *reinterpret_cast<const u64*>(&slab[mcol*28 + quad*8 + 4]) : 0ull;
    f32x4 d = __builtin_amdgcn_mfma_f32_16x16x32_bf16(a_pre.v, bs.v, z4, 0, 0, 0);
    float mv = maskS[mcol];
    float e0 = exp2f(d[0] + rs_[0]*mv);
    float e1 = exp2f(d[1] + rs_[1]*mv);
    float e2 = exp2f(d[2] + rs_[2]*mv);
    float e3 = exp2f(d[3] + rs_[3]*mv);
    Lacc[0] += e0; Lacc[1] += e1; Lacc[2] += e2; Lacc[3] += e3;
    u64 pk = (u64)f2bf(e0) | ((u64)f2bf(e1) << 16)
           | ((u64)f2bf(e2) << 32) | ((u64)f2bf(e3) << 48);
    *reinterpret_cast<u64*>(&slab[mcol*28 + quad*4]) = pk;   // E slot = g
  }

  // reduce L over m (cl bits within wave, then cross-wave via LDS)
  #pragma unroll
  for (int r = 0; r < 4; r++){
    float v = Lacc[r];
    v += __shfl_xor(v, 1); v += __shfl_xor(v, 2);
    v += __shfl_xor(v, 4); v += __shfl_xor(v, 8);
    Lacc[r] = v;
  }
  if (cl == 0){
    #pragma unroll
    for (int r = 0; r < 4; r++) Lred[wv][quad*4 + r] = Lacc[r];
  }
  __syncthreads();
  if (t < 16) invLs[t] = 1.f / (Lred[0][t] + Lred[1][t] + Lred[2][t] + Lred[3][t]);
  __syncthreads();

  FragU a_post;
  #pragma unroll
  for (int j = 0; j < 8; j++){
    int k = quad*8 + j;   // k = g
    a_post.s[j] = (cl < 12 && k < 12) ? f2bf(w_post[cl*12 + k] * invLs[k]) : (u16)0;
  }

  // postmix sweep: E read back (quads 0,1 only; upper K zero), MFMA, store
  #pragma unroll
  for (int j = 0; j < 16; j++){
    int mcol = wv*256 + j*16 + cl;
    FragU be;
    be.d[0] = qlo ? *reinterpret_cast<const u64*>(&slab[mcol*28 + quad*8])     : 0ull;
    be.d[1] = qlo ? *reinterpret_cast<const u64*>(&slab[mcol*28 + quad*8 + 4]) : 0ull;
    f32x4 d = __builtin_amdgcn_mfma_f32_16x16x32_bf16(a_post.v, be.v, z4, 0, 0, 0);
    if (quad < 3){
      #pragma unroll
      for (int r = 0; r < 4; r++){
        int h = quad*4 + r;
        S[((long)((b*12 + h)*1024 + n))*1024 + mcol] = f2bf(d[r]);
      }
    }
  }
}

extern "C" void kernel_launch(void* const* d_in, const int* in_sizes, int n_in,
                              void* d_out, int out_size, void* d_ws, size_t ws_size,
                              hipStream_t stream)
{
  const float* x      = (const float*)d_in[0];
  const float* mask   = (const float*)d_in[1];
  const float* w_qkv  = (const float*)d_in[2];
  const float* w_proj = (const float*)d_in[3];
  const float* b_proj = (const float*)d_in[4];
  const float* w_pre  = (const float*)d_in[5];
  const float* w_post = (const float*)d_in[6];
  float* out = (float*)d_out;

  u16* xb     = (u16*)d_ws;
  u16* wqkvb  = xb     + 4096l*768;
  u16* wprojb = wqkvb  + 2304l*768;
  u16* Qb     = wprojb + 768l*768;
  u16* Kb     = Qb     + 48l*1024*64;
  u16* Vtb    = Kb     + 48l*1024*64;
  u16* tmpb   = Vtb    + 48l*1024*64;
  u16* Sb     = tmpb   + 4096l*768;
  size_t need = ((size_t)(Sb - xb) + 48ul*1024*1024) * sizeof(u16);
  if (ws_size < need) return;

  cvt_kernel<<<(4096*768/4 + 255)/256, 256, 0, stream>>>(x,      xb,     4096*768/4);
  cvt_kernel<<<(2304*768/4 + 255)/256, 256, 0, stream>>>(w_qkv,  wqkvb,  2304*768/4);
  cvt_kernel<<<(768*768/4  + 255)/256, 256, 0, stream>>>(w_proj, wprojb, 768*768/4);

  dim3 gq(4096/128, 2304/128, 1);
  gemm_bt<128,128,32,0><<<gq, 256, 0, stream>>>(xb, wqkvb, Qb, Kb, Vtb, nullptr,
      4096, 2304, 768, 768, 768, 0, 0, 0);

  dim3 gs(1024/128, 1024/128, 48);
  gemm_bt<128,128,64,1><<<gs, 256, 0, stream>>>(Qb, Kb, Sb, nullptr, nullptr, nullptr,
      1024, 1024, 64, 64, 64, 1024l*64, 1024l*64, 1024l*1024);

  mix3_kernel<<<4096, 256, 0, stream>>>(Sb, mask, w_pre, w_post);

  dim3 gp(1024/128, 1, 48);
  gemm_bt<128,64,64,2><<<gp, 256, 0, stream>>>(Sb, Vtb, tmpb, nullptr, nullptr, nullptr,
      1024, 64, 1024, 1024, 1024, 1024l*1024, 64l*1024, 0);

  dim3 go(4096/128, 768/64, 1);
  gemm_bt<128,64,32,3><<<go, 256, 0, stream>>>(tmpb, wprojb, out, nullptr, nullptr, b_proj,
      4096, 768, 768, 768, 768, 0, 0, 0);
}